// Round 3
// baseline (41.859 us; speedup 1.0000x reference)
//
#include <hip/hip_runtime.h>

// out[b, e] = sum_d x[b, d] * T[g[b] % G, d, e]
// B=128, D=1024, G=40, all float32.
//
// Group samples by gi = g[b] % 40 (avg 3.2 samples/matrix) so each T element
// is read ~once (compulsory ~160 MB). Split D into 32 chunks for occupancy
// (1280 blocks = 5 waves/SIMD); 8-deep register prefetch pipeline on T rows
// for memory-level parallelism. Partials in d_ws, deterministic reduce.

#define B_DIM   128
#define D_DIM   1024
#define G_DIM   40
#define DSPLIT  32
#define DCHUNK  (D_DIM / DSPLIT)   // 32 rows of T per block
#define SMAX    8                  // samples per pass
#define THREADS 256                // 256 threads * float4 = 1024 columns
#define PF      8                  // prefetch depth (rows in flight)

template <int USE_ATOMIC>
__global__ __launch_bounds__(THREADS) void leqfc_grouped(
    const float* __restrict__ x,
    const int* __restrict__ g,
    const float* __restrict__ T,
    float* __restrict__ part,
    float* __restrict__ out)
{
    const int gi    = blockIdx.x;      // group 0..39
    const int dc    = blockIdx.y;      // d-chunk 0..DSPLIT-1
    const int dbase = dc * DCHUNK;
    const int tid   = threadIdx.x;

    __shared__ int   mem[B_DIM];
    __shared__ int   cnt;
    __shared__ float xs[SMAX][DCHUNK]; // 1 KB

    if (tid == 0) cnt = 0;
    __syncthreads();
    if (tid < B_DIM) {
        if ((g[tid] % G_DIM) == gi) {
            int i = atomicAdd(&cnt, 1);
            mem[i] = tid;
        }
    }
    __syncthreads();
    const int m = cnt;

    const float* __restrict__ Tg = T + (size_t)gi * D_DIM * D_DIM;
    const float4* __restrict__ Trow =
        reinterpret_cast<const float4*>(Tg + (size_t)dbase * D_DIM) + tid;

    for (int s0 = 0; s0 < m; s0 += SMAX) {
        const int mc = min(SMAX, m - s0);

        __syncthreads(); // previous pass' xs consumers done
        {
            // SMAX*DCHUNK = 256 floats; one per thread
            int j  = tid >> 5;          // / DCHUNK
            int dd = tid & (DCHUNK - 1);
            xs[j][dd] = (j < mc)
                ? x[(size_t)mem[s0 + j] * D_DIM + dbase + dd]
                : 0.0f;
        }
        __syncthreads();

        float4 acc[SMAX];
        #pragma unroll
        for (int j = 0; j < SMAX; ++j) acc[j] = make_float4(0.f, 0.f, 0.f, 0.f);

        // 8-deep software prefetch pipeline over the DCHUNK T rows
        float4 tbuf[PF];
        #pragma unroll
        for (int k = 0; k < PF; ++k)
            tbuf[k] = Trow[(size_t)k * (D_DIM / 4)];

        #pragma unroll
        for (int dd0 = 0; dd0 < DCHUNK; dd0 += PF) {
            #pragma unroll
            for (int k = 0; k < PF; ++k) {
                float4 t = tbuf[k];
                if (dd0 + PF + k < DCHUNK)          // static predicate (unrolled)
                    tbuf[k] = Trow[(size_t)(dd0 + PF + k) * (D_DIM / 4)];
                const int dd = dd0 + k;
                #pragma unroll
                for (int j = 0; j < SMAX; ++j) {
                    const float xv = xs[j][dd];     // LDS broadcast
                    acc[j].x = fmaf(xv, t.x, acc[j].x);
                    acc[j].y = fmaf(xv, t.y, acc[j].y);
                    acc[j].z = fmaf(xv, t.z, acc[j].z);
                    acc[j].w = fmaf(xv, t.w, acc[j].w);
                }
            }
        }

        #pragma unroll
        for (int j = 0; j < SMAX; ++j) {   // static index; predicated store
            if (j < mc) {
                const int b = mem[s0 + j];
                if (USE_ATOMIC) {
                    float* o = out + (size_t)b * D_DIM + tid * 4;
                    atomicAdd(o + 0, acc[j].x);
                    atomicAdd(o + 1, acc[j].y);
                    atomicAdd(o + 2, acc[j].z);
                    atomicAdd(o + 3, acc[j].w);
                } else {
                    float4* o = reinterpret_cast<float4*>(
                        part + ((size_t)dc * B_DIM + b) * D_DIM) + tid;
                    *o = acc[j];
                }
            }
        }
    }
}

__global__ __launch_bounds__(256) void leqfc_reduce(
    const float* __restrict__ part, float* __restrict__ out)
{
    const int idx = blockIdx.x * 256 + threadIdx.x;  // over B*D/4 float4 slots
    const float4* p4 = reinterpret_cast<const float4*>(part);
    float4 s = make_float4(0.f, 0.f, 0.f, 0.f);
    #pragma unroll
    for (int p = 0; p < DSPLIT; ++p) {
        float4 v = p4[(size_t)p * (B_DIM * D_DIM / 4) + idx];
        s.x += v.x; s.y += v.y; s.z += v.z; s.w += v.w;
    }
    reinterpret_cast<float4*>(out)[idx] = s;
}

__global__ __launch_bounds__(256) void leqfc_zero(float* __restrict__ out)
{
    out[blockIdx.x * 256 + threadIdx.x] = 0.f;
}

extern "C" void kernel_launch(void* const* d_in, const int* in_sizes, int n_in,
                              void* d_out, int out_size, void* d_ws, size_t ws_size,
                              hipStream_t stream)
{
    const float* x = (const float*)d_in[0];
    const int*   g = (const int*)d_in[1];
    const float* T = (const float*)d_in[2];
    float* out = (float*)d_out;

    const size_t need = (size_t)DSPLIT * B_DIM * D_DIM * sizeof(float); // 16.8 MB
    dim3 grid(G_DIM, DSPLIT);

    if (ws_size >= need) {
        float* part = (float*)d_ws;
        leqfc_grouped<0><<<grid, THREADS, 0, stream>>>(x, g, T, part, nullptr);
        leqfc_reduce<<<(B_DIM * D_DIM / 4) / 256, 256, 0, stream>>>(part, out);
    } else {
        leqfc_zero<<<(B_DIM * D_DIM) / 256, 256, 0, stream>>>(out);
        leqfc_grouped<1><<<grid, THREADS, 0, stream>>>(x, g, T, nullptr, out);
    }
}

// Round 4
// 31.157 us; speedup vs baseline: 1.3435x; 1.3435x over previous
//
#include <hip/hip_runtime.h>

// out[b, e] = sum_d x[b, d] * T[g[b] % G, d, e]
// B=128, D=1024, G=40, f32.
//
// Single fused kernel. Block = (group gi, 64-column stripe). Threads
// 256 = 16 d-slices x 16 e-threads; each thread owns 4 cols (float4) and
// 64 rows of its group's matrix; partial sums are reduced across the 16
// d-slices in LDS (red buffer aliases the xs buffer), then written to out.
// No global partials, no reduce kernel. Compulsory traffic ~= one pass
// over the 160 MB table (HBM roofline ~26 us; less if L3 retains T).

#define B_DIM   128
#define D_DIM   1024
#define G_DIM   40
#define SMAX    8      // samples per pass (avg group size 3.2, max ~10)
#define ECH     16     // column chunks
#define ECOLS   64     // columns per block
#define DSL     16     // d-slices per block
#define THREADS 256    // DSL x 16 e-threads

__global__ __launch_bounds__(THREADS) void leqfc_fused(
    const float* __restrict__ x,
    const int* __restrict__ g,
    const float* __restrict__ T,
    float* __restrict__ out)
{
    const int gi  = blockIdx.x;          // 0..39
    const int e0  = blockIdx.y * ECOLS;  // column stripe base
    const int tid = threadIdx.x;
    const int sl  = tid >> 4;            // d-slice 0..15 (rows sl*64 .. +63)
    const int eth = tid & 15;            // e-thread: cols e0 + eth*4 .. +3

    // xs[8][1024] (32 KB) during the d-loop; red[8][16][64] (32 KB) after.
    __shared__ float smem[SMAX * D_DIM];
    __shared__ int   mem[B_DIM];
    __shared__ int   cnt;

    if (tid == 0) cnt = 0;
    __syncthreads();
    if (tid < B_DIM) {
        if ((g[tid] % G_DIM) == gi) {
            mem[atomicAdd(&cnt, 1)] = tid;   // slot order races, but per-sample
        }                                    // numerics are slot-invariant
    }
    __syncthreads();
    const int m = cnt;

    const float4* __restrict__ x4 = reinterpret_cast<const float4*>(x);
    const float4* __restrict__ Tp = reinterpret_cast<const float4*>(
        T + (size_t)gi * D_DIM * D_DIM + (size_t)(sl * 64) * D_DIM + e0) + eth;
    float4* smem4 = reinterpret_cast<float4*>(smem);

    for (int s0 = 0; s0 < m; s0 += SMAX) {
        const int mc = min(SMAX, m - s0);

        __syncthreads();   // previous pass done with smem
        // stage xs[j][0..1023] for mc samples: 2048 float4 slots, 8/thread
        #pragma unroll
        for (int k = 0; k < 8; ++k) {
            const int fq = tid + k * THREADS;   // 0..2047
            const int j  = fq >> 8;
            const int dq = fq & 255;
            smem4[fq] = (j < mc) ? x4[(size_t)mem[s0 + j] * (D_DIM / 4) + dq]
                                 : make_float4(0.f, 0.f, 0.f, 0.f);
        }
        __syncthreads();

        float4 acc[SMAX];
        #pragma unroll
        for (int j = 0; j < SMAX; ++j) acc[j] = make_float4(0.f, 0.f, 0.f, 0.f);

        // 64 rows per thread, 4 rows per iteration
        #pragma unroll 4
        for (int k = 0; k < 16; ++k) {
            const float4 t0 = Tp[(size_t)(4 * k + 0) * (D_DIM / 4)];
            const float4 t1 = Tp[(size_t)(4 * k + 1) * (D_DIM / 4)];
            const float4 t2 = Tp[(size_t)(4 * k + 2) * (D_DIM / 4)];
            const float4 t3 = Tp[(size_t)(4 * k + 3) * (D_DIM / 4)];
            const int dq = sl * 16 + k;   // float4 index of rows 4k..4k+3 in xs
            #pragma unroll
            for (int j = 0; j < SMAX; ++j) {
                const float4 xv = smem4[j * (D_DIM / 4) + dq];  // broadcast read
                acc[j].x = fmaf(xv.x, t0.x, fmaf(xv.y, t1.x, fmaf(xv.z, t2.x, fmaf(xv.w, t3.x, acc[j].x))));
                acc[j].y = fmaf(xv.x, t0.y, fmaf(xv.y, t1.y, fmaf(xv.z, t2.y, fmaf(xv.w, t3.y, acc[j].y))));
                acc[j].z = fmaf(xv.x, t0.z, fmaf(xv.y, t1.z, fmaf(xv.z, t2.z, fmaf(xv.w, t3.z, acc[j].z))));
                acc[j].w = fmaf(xv.x, t0.w, fmaf(xv.y, t1.w, fmaf(xv.z, t2.w, fmaf(xv.w, t3.w, acc[j].w))));
            }
        }

        __syncthreads();   // all xs reads complete; smem becomes red[]
        #pragma unroll
        for (int j = 0; j < SMAX; ++j)
            smem4[(j * DSL + sl) * (ECOLS / 4) + eth] = acc[j];
        __syncthreads();

        // fold 16 d-slices: 512 outputs (8 samples x 64 cols), 2 per thread
        #pragma unroll
        for (int o2 = 0; o2 < 2; ++o2) {
            const int o = tid + o2 * THREADS;   // 0..511
            const int j = o >> 6;
            const int c = o & 63;
            if (j < mc) {
                float s = 0.f;
                #pragma unroll
                for (int ss = 0; ss < DSL; ++ss)
                    s += smem[(j * DSL + ss) * ECOLS + c];
                out[(size_t)mem[s0 + j] * D_DIM + e0 + c] = s;
            }
        }
    }
}

extern "C" void kernel_launch(void* const* d_in, const int* in_sizes, int n_in,
                              void* d_out, int out_size, void* d_ws, size_t ws_size,
                              hipStream_t stream)
{
    const float* x = (const float*)d_in[0];
    const int*   g = (const int*)d_in[1];
    const float* T = (const float*)d_in[2];
    float* out = (float*)d_out;

    dim3 grid(G_DIM, ECH);   // 40 x 16 = 640 blocks
    leqfc_fused<<<grid, THREADS, 0, stream>>>(x, g, T, out);
}